// Round 9
// baseline (81.397 us; speedup 1.0000x reference)
//
#include <hip/hip_runtime.h>

// EdgeNetwork: out[e] = sigmoid( tanh( [x[col[e]], x[row[e]]] @ W1 + b1 ) @ W2 + b2 )
// E = 3.2M, IN=16, HID=64.
//
// R9 (base = R8): transcendental elimination.
//  - tanh via Pade(7,6) rational (err <= 5e-5 for |h|<=4.6, <=1.2e-3 at |h|=7;
//    data max |h| ~ 6.3). Removes all 64 v_exp_f32 per pair (~16cy each = half
//    of VALU busy, the term untouched since R2 and why R5/R6 nulled).
//  - Polynomials on f32x2 via FORCED v_pk_fma_f32 / v_pk_mul_f32 / v_pk_add_f32
//    inline asm (dual-issue f32; compiler doesn't form them from scalar IR).
//  - Quad common-denominator tree kept: 1 v_rcp per 4 h (variable numerators).
//  - b1/W2 as per-lane f32x2 register pairs (natural pk operands); no LDS.
// Carried from R8: 32-edge mfma_32x32x16 swapped-operand tiles, pair-unroll
// (64 edges/iter), select-before-reduce single shfl, coalesced 64-lane store,
// 32-bit addressing, 2-deep prefetch, asm exp2/rcp for the one sigmoid.

typedef __attribute__((ext_vector_type(8)))  short bf16x8;
typedef __attribute__((ext_vector_type(2)))  float f32x2;
typedef __attribute__((ext_vector_type(4)))  float f32x4;
typedef __attribute__((ext_vector_type(16))) float f32x16;
typedef __attribute__((ext_vector_type(4)))  unsigned short u16x4;

#define LOG2E 1.4426950408889634f

__device__ __forceinline__ float asm_exp2(float x) {
    float r;
    asm("v_exp_f32 %0, %1" : "=v"(r) : "v"(x));
    return r;
}
__device__ __forceinline__ float asm_rcp(float x) {
    float r;
    asm("v_rcp_f32 %0, %1" : "=v"(r) : "v"(x));
    return r;
}
// Packed f32 (VOP3P dual-issue): guaranteed single instructions.
__device__ __forceinline__ f32x2 pk_add(f32x2 a, f32x2 b) {
    f32x2 d;
    asm("v_pk_add_f32 %0, %1, %2" : "=v"(d) : "v"(a), "v"(b));
    return d;
}
__device__ __forceinline__ f32x2 pk_mul(f32x2 a, f32x2 b) {
    f32x2 d;
    asm("v_pk_mul_f32 %0, %1, %2" : "=v"(d) : "v"(a), "v"(b));
    return d;
}
__device__ __forceinline__ f32x2 pk_fma(f32x2 a, f32x2 b, f32x2 c) {
    f32x2 d;
    asm("v_pk_fma_f32 %0, %1, %2, %3" : "=v"(d) : "v"(a), "v"(b), "v"(c));
    return d;
}

template <bool B> struct BC { static constexpr bool value = B; };

__device__ __forceinline__ unsigned short f2bf(float f) {
    unsigned u = __float_as_uint(f);
    u += 0x7fffu + ((u >> 16) & 1u);
    return (unsigned short)(u >> 16);
}

// ---- x fp32 -> bf16, plus edge_index dtype detection (block 0, wave 0) ----
__global__ void prep(const float* __restrict__ x, unsigned short* __restrict__ xb, int n,
                     const unsigned* __restrict__ ei, int* __restrict__ flag) {
    if (blockIdx.x == 0 && threadIdx.x < 64) {
        unsigned v = ei[2 * threadIdx.x + 1];          // odd 32-bit words
        unsigned long long nz = __ballot(v != 0u);
        if (threadIdx.x == 0) flag[0] = (nz == 0ull) ? 1 : 0;
    }
    int i = (blockIdx.x * blockDim.x + threadIdx.x) * 4;
    if (i >= n) return;
    f32x4 v = *(const f32x4*)(x + i);
    u16x4 o;
    o[0] = f2bf(v[0]); o[1] = f2bf(v[1]); o[2] = f2bf(v[2]); o[3] = f2bf(v[3]);
    *(u16x4*)(xb + i) = o;
}

__global__ void detect_idx64(const unsigned* __restrict__ ei, int* __restrict__ flag) {
    unsigned v = ei[2 * threadIdx.x + 1];
    unsigned long long nz = __ballot(v != 0u);
    if (threadIdx.x == 0) flag[0] = (nz == 0ull) ? 1 : 0;
}

struct IdxPair { int c, r; };

// Pade(7,6) tanh coefficients (shared num/den c0).
#define PC0 135135.0f
#define PC1 17325.0f
#define PC2 378.0f
#define PD1 62370.0f
#define PD2 3150.0f
#define PD3 28.0f

// ===================== pair kernel (E % 64 == 0) =====================
template <bool USE_XB>
__global__ void __launch_bounds__(256)
edge_mlp_pair(const void* __restrict__ ei,
              const float* __restrict__ x,
              const unsigned short* __restrict__ xb,
              const float* __restrict__ W1,
              const float* __restrict__ b1,
              const float* __restrict__ W2,
              const float* __restrict__ b2,
              float* __restrict__ out,
              const int* __restrict__ flag,
              int E, int npairs)
{
    const int lane = threadIdx.x & 63;
    const int l31  = lane & 31;
    const int g    = lane >> 5;
    const int gwave  = blockIdx.x * (blockDim.x >> 6) + (threadIdx.x >> 6);
    const int nwaves = gridDim.x * (blockDim.x >> 6);

    const int idx64 = flag ? flag[0] : 0;

    // A-fragments of W1T (unscaled)
    bf16x8 w1f00, w1f01, w1f10, w1f11;
    {
        union { bf16x8 v; unsigned short u[8]; } t00, t01, t10, t11;
#pragma unroll
        for (int b = 0; b < 8; ++b) {
            int k0 = 8 * g + b;
            t00.u[b] = f2bf(W1[(k0)      * 64 + l31]);
            t01.u[b] = f2bf(W1[(16 + k0) * 64 + l31]);
            t10.u[b] = f2bf(W1[(k0)      * 64 + 32 + l31]);
            t11.u[b] = f2bf(W1[(16 + k0) * 64 + 32 + l31]);
        }
        w1f00 = t00.v; w1f01 = t01.v; w1f10 = t10.v; w1f11 = t11.v;
    }

    // Per-lane (b1, W2) register pairs: acc half blk, h-pair m covers rows
    // rowv(2m), rowv(2m)+1 of hid block blk.
    f32x2 b1p[16], w2p[16];
#pragma unroll
    for (int blk = 0; blk < 2; ++blk) {
#pragma unroll
        for (int m = 0; m < 8; ++m) {
            int j = 2 * m;
            int rowv = (j & 3) + 8 * (j >> 2) + 4 * g;
            int h0 = blk * 32 + rowv;
            b1p[blk * 8 + m] = f32x2{ b1[h0], b1[h0 + 1] };
            w2p[blk * 8 + m] = f32x2{ W2[h0], W2[h0 + 1] };
        }
    }
    const float bias2 = b2[0];

    // Pade coefficient splats (loop-invariant VGPR pairs for the asm pk ops)
    const f32x2 c0  = { PC0, PC0 };
    const f32x2 c1  = { PC1, PC1 };
    const f32x2 c2  = { PC2, PC2 };
    const f32x2 d1  = { PD1, PD1 };
    const f32x2 d2  = { PD2, PD2 };
    const f32x2 d3  = { PD3, PD3 };

    const char* xbb  = (const char*)xb;
    const char* outb = (char*)out;
    const unsigned g16 = (unsigned)g << 4;

    auto body = [&](auto bc) {
        constexpr bool IDX64 = decltype(bc)::value;
        const unsigned sh = IDX64 ? 3u : 2u;
        const char* eiR = (const char*)ei;
        const char* eiC = (const char*)ei + ((size_t)E << sh);

        auto load_idx4 = [&](int pp, IdxPair& a, IdxPair& b) {
            unsigned base  = (((unsigned)pp << 6) + (unsigned)l31) << sh;
            unsigned baseB = base + (32u << sh);
            a.r = *(const int*)(eiR + base);
            a.c = *(const int*)(eiC + base);
            b.r = *(const int*)(eiR + baseB);
            b.c = *(const int*)(eiC + baseB);
        };
        auto gather = [&](int node) -> bf16x8 {
            if (USE_XB) {
                unsigned off = ((unsigned)node << 5) + g16;
                return *(const bf16x8*)(xbb + off);
            } else {
                const float* px = x + (size_t)node * 16 + 8 * g;
                f32x4 v0 = *(const f32x4*)px;
                f32x4 v1 = *(const f32x4*)(px + 4);
                union { bf16x8 v; unsigned short u[8]; } t;
#pragma unroll
                for (int b = 0; b < 4; ++b) { t.u[b] = f2bf(v0[b]); t.u[b + 4] = f2bf(v1[b]); }
                return t.v;
            }
        };

        // quad: p += sum over 4 h of w2*tanh(h+b1), Pade(7,6), 1 rcp per quad.
        auto quad = [&](const f32x16& A, int j0, int mb, float& p) {
            f32x2 hA = pk_add(f32x2{ A[j0],     A[j0 + 1] }, b1p[mb]);
            f32x2 hB = pk_add(f32x2{ A[j0 + 2], A[j0 + 3] }, b1p[mb + 1]);
            f32x2 sA = pk_mul(hA, hA);
            f32x2 sB = pk_mul(hB, hB);
            // num inner: c0 + s*(c1 + s*(c2 + s))
            f32x2 nA = pk_add(c2, sA);
            nA = pk_fma(sA, nA, c1);
            nA = pk_fma(sA, nA, c0);
            f32x2 nB = pk_add(c2, sB);
            nB = pk_fma(sB, nB, c1);
            nB = pk_fma(sB, nB, c0);
            // den: c0 + s*(d1 + s*(d2 + s*d3))
            f32x2 dA = pk_fma(sA, d3, d2);
            dA = pk_fma(sA, dA, d1);
            dA = pk_fma(sA, dA, c0);
            f32x2 dB = pk_fma(sB, d3, d2);
            dB = pk_fma(sB, dB, d1);
            dB = pk_fma(sB, dB, c0);
            // num = (w2*h) * num_inner
            f32x2 numA = pk_mul(pk_mul(w2p[mb],     hA), nA);
            f32x2 numB = pk_mul(pk_mul(w2p[mb + 1], hB), nB);
            // common-denominator combine (scalar tree, 1 rcp)
            float D01 = dA[0] * dA[1];
            float D23 = dB[0] * dB[1];
            float N01 = fmaf(numA[0], dA[1], numA[1] * dA[0]);
            float N23 = fmaf(numB[0], dB[1], numB[1] * dB[0]);
            float N   = fmaf(N01, D23, N23 * D01);
            float P   = D01 * D23;
            p = fmaf(N, asm_rcp(P), p);
        };

        int pp = gwave;
        if (pp >= npairs) return;
        IdxPair iA, iB;
        load_idx4(pp, iA, iB);
        bf16x8 fcA = gather(iA.c), frA = gather(iA.r);
        bf16x8 fcB = gather(iB.c), frB = gather(iB.r);
        int pn = pp + nwaves;
        IdxPair iAn, iBn;
        load_idx4(pn < npairs ? pn : npairs - 1, iAn, iBn);

        const f32x16 ZC = 0.0f;

        while (true) {
            // prefetch: gathers for pair+1, indices for pair+2
            bf16x8 fcAn = gather(iAn.c), frAn = gather(iAn.r);
            bf16x8 fcBn = gather(iBn.c), frBn = gather(iBn.r);
            int pnn = pn + nwaves;
            IdxPair iAnn, iBnn;
            load_idx4(pnn < npairs ? pnn : npairs - 1, iAnn, iBnn);

            // ---- tile A ----
            float pA = 0.0f;
            {
                f32x16 a0 = __builtin_amdgcn_mfma_f32_32x32x16_bf16(w1f00, fcA, ZC, 0, 0, 0);
                a0        = __builtin_amdgcn_mfma_f32_32x32x16_bf16(w1f01, frA, a0, 0, 0, 0);
                f32x16 a1 = __builtin_amdgcn_mfma_f32_32x32x16_bf16(w1f10, fcA, ZC, 0, 0, 0);
                a1        = __builtin_amdgcn_mfma_f32_32x32x16_bf16(w1f11, frA, a1, 0, 0, 0);
#pragma unroll
                for (int q = 0; q < 4; ++q) quad(a0, q * 4, 2 * q,     pA);
#pragma unroll
                for (int q = 0; q < 4; ++q) quad(a1, q * 4, 8 + 2 * q, pA);
            }
            // ---- tile B ----
            float pB = 0.0f;
            {
                f32x16 a0 = __builtin_amdgcn_mfma_f32_32x32x16_bf16(w1f00, fcB, ZC, 0, 0, 0);
                a0        = __builtin_amdgcn_mfma_f32_32x32x16_bf16(w1f01, frB, a0, 0, 0, 0);
                f32x16 a1 = __builtin_amdgcn_mfma_f32_32x32x16_bf16(w1f10, fcB, ZC, 0, 0, 0);
                a1        = __builtin_amdgcn_mfma_f32_32x32x16_bf16(w1f11, frB, a1, 0, 0, 0);
#pragma unroll
                for (int q = 0; q < 4; ++q) quad(a0, q * 4, 2 * q,     pB);
#pragma unroll
                for (int q = 0; q < 4; ++q) quad(a1, q * 4, 8 + 2 * q, pB);
            }

            // select-before-reduce: lane's own tile partial + cross partial from lane^32
            float own   = g ? pB : pA;
            float cross = g ? pA : pB;
            own += __shfl_xor(cross, 32);
            float z = own + bias2;
            float res = asm_rcp(1.0f + asm_exp2(-z * LOG2E));

            // e = pp*64 + lane: one unpredicated, fully-coalesced 256B store
            unsigned eoff = (((unsigned)pp << 6) + (unsigned)lane) << 2;
            *(float*)(outb + eoff) = res;

            if (pn >= npairs) break;
            pp = pn; pn = pnn;
            iAn = iAnn; iBn = iBnn;
            fcA = fcAn; frA = frAn; fcB = fcBn; frB = frBn;
        }
    };

    if (idx64) body(BC<true>{});
    else       body(BC<false>{});
}

// ===================== fallback single-tile kernel (E % 64 != 0) =====================
template <bool USE_XB, bool EXACT>
__global__ void __launch_bounds__(256)
edge_mlp1(const void* __restrict__ ei,
          const float* __restrict__ x,
          const unsigned short* __restrict__ xb,
          const float* __restrict__ W1,
          const float* __restrict__ b1,
          const float* __restrict__ W2,
          const float* __restrict__ b2,
          float* __restrict__ out,
          const int* __restrict__ flag,
          int E, int ntiles)
{
    const int lane = threadIdx.x & 63;
    const int l31  = lane & 31;
    const int g    = lane >> 5;
    const int gwave  = blockIdx.x * (blockDim.x >> 6) + (threadIdx.x >> 6);
    const int nwaves = gridDim.x * (blockDim.x >> 6);

    const int idx64 = flag ? flag[0] : 0;

    bf16x8 w1f00, w1f01, w1f10, w1f11;
    {
        union { bf16x8 v; unsigned short u[8]; } t00, t01, t10, t11;
#pragma unroll
        for (int b = 0; b < 8; ++b) {
            int k0 = 8 * g + b;
            t00.u[b] = f2bf(W1[(k0)      * 64 + l31]);
            t01.u[b] = f2bf(W1[(16 + k0) * 64 + l31]);
            t10.u[b] = f2bf(W1[(k0)      * 64 + 32 + l31]);
            t11.u[b] = f2bf(W1[(16 + k0) * 64 + 32 + l31]);
        }
        w1f00 = t00.v; w1f01 = t01.v; w1f10 = t10.v; w1f11 = t11.v;
    }

    f32x2 b1p[16], w2p[16];
#pragma unroll
    for (int blk = 0; blk < 2; ++blk) {
#pragma unroll
        for (int m = 0; m < 8; ++m) {
            int j = 2 * m;
            int rowv = (j & 3) + 8 * (j >> 2) + 4 * g;
            int h0 = blk * 32 + rowv;
            b1p[blk * 8 + m] = f32x2{ b1[h0], b1[h0 + 1] };
            w2p[blk * 8 + m] = f32x2{ W2[h0], W2[h0 + 1] };
        }
    }
    const float bias2 = b2[0];

    const f32x2 c0  = { PC0, PC0 };
    const f32x2 c1  = { PC1, PC1 };
    const f32x2 c2  = { PC2, PC2 };
    const f32x2 d1  = { PD1, PD1 };
    const f32x2 d2  = { PD2, PD2 };
    const f32x2 d3  = { PD3, PD3 };

    const char* xbb  = (const char*)xb;
    const char* outb = (char*)out;
    const unsigned g16 = (unsigned)g << 4;

    auto body = [&](auto bc) {
        constexpr bool IDX64 = decltype(bc)::value;
        const unsigned sh = IDX64 ? 3u : 2u;
        const char* eiR = (const char*)ei;
        const char* eiC = (const char*)ei + ((size_t)E << sh);

        auto load_idx = [&](int tt) -> IdxPair {
            int e = tt * 32 + l31;
            unsigned ec;
            if (EXACT) ec = (unsigned)e;
            else       ec = (unsigned)(e < E ? e : E - 1);
            unsigned off = ec << sh;
            IdxPair ip;
            ip.r = *(const int*)(eiR + off);
            ip.c = *(const int*)(eiC + off);
            return ip;
        };
        auto gather = [&](int node) -> bf16x8 {
            if (USE_XB) {
                unsigned off = ((unsigned)node << 5) + g16;
                return *(const bf16x8*)(xbb + off);
            } else {
                const float* px = x + (size_t)node * 16 + 8 * g;
                f32x4 v0 = *(const f32x4*)px;
                f32x4 v1 = *(const f32x4*)(px + 4);
                union { bf16x8 v; unsigned short u[8]; } t;
#pragma unroll
                for (int b = 0; b < 4; ++b) { t.u[b] = f2bf(v0[b]); t.u[b + 4] = f2bf(v1[b]); }
                return t.v;
            }
        };

        auto quad = [&](const f32x16& A, int j0, int mb, float& p) {
            f32x2 hA = pk_add(f32x2{ A[j0],     A[j0 + 1] }, b1p[mb]);
            f32x2 hB = pk_add(f32x2{ A[j0 + 2], A[j0 + 3] }, b1p[mb + 1]);
            f32x2 sA = pk_mul(hA, hA);
            f32x2 sB = pk_mul(hB, hB);
            f32x2 nA = pk_add(c2, sA);
            nA = pk_fma(sA, nA, c1);
            nA = pk_fma(sA, nA, c0);
            f32x2 nB = pk_add(c2, sB);
            nB = pk_fma(sB, nB, c1);
            nB = pk_fma(sB, nB, c0);
            f32x2 dA = pk_fma(sA, d3, d2);
            dA = pk_fma(sA, dA, d1);
            dA = pk_fma(sA, dA, c0);
            f32x2 dB = pk_fma(sB, d3, d2);
            dB = pk_fma(sB, dB, d1);
            dB = pk_fma(sB, dB, c0);
            f32x2 numA = pk_mul(pk_mul(w2p[mb],     hA), nA);
            f32x2 numB = pk_mul(pk_mul(w2p[mb + 1], hB), nB);
            float D01 = dA[0] * dA[1];
            float D23 = dB[0] * dB[1];
            float N01 = fmaf(numA[0], dA[1], numA[1] * dA[0]);
            float N23 = fmaf(numB[0], dB[1], numB[1] * dB[0]);
            float N   = fmaf(N01, D23, N23 * D01);
            float P   = D01 * D23;
            p = fmaf(N, asm_rcp(P), p);
        };

        int t = gwave;
        if (t >= ntiles) return;
        IdxPair ic = load_idx(t);
        bf16x8 fc = gather(ic.c);
        bf16x8 fr = gather(ic.r);
        int tn = t + nwaves;
        IdxPair inx = load_idx(tn < ntiles ? tn : ntiles - 1);

        const f32x16 ZC = 0.0f;

        while (true) {
            bf16x8 fcn = gather(inx.c);
            bf16x8 frn = gather(inx.r);
            int tnn = tn + nwaves;
            IdxPair inn = load_idx(tnn < ntiles ? tnn : ntiles - 1);

            f32x16 acc0 = __builtin_amdgcn_mfma_f32_32x32x16_bf16(w1f00, fc, ZC, 0, 0, 0);
            acc0        = __builtin_amdgcn_mfma_f32_32x32x16_bf16(w1f01, fr, acc0, 0, 0, 0);
            f32x16 acc1 = __builtin_amdgcn_mfma_f32_32x32x16_bf16(w1f10, fc, ZC, 0, 0, 0);
            acc1        = __builtin_amdgcn_mfma_f32_32x32x16_bf16(w1f11, fr, acc1, 0, 0, 0);

            float p = 0.0f;
#pragma unroll
            for (int q = 0; q < 4; ++q) quad(acc0, q * 4, 2 * q,     p);
#pragma unroll
            for (int q = 0; q < 4; ++q) quad(acc1, q * 4, 8 + 2 * q, p);

            p += __shfl_xor(p, 32);
            float z = p + bias2;
            float res = asm_rcp(1.0f + asm_exp2(-z * LOG2E));

            unsigned eoff = ((unsigned)(t * 32 + l31)) << 2;
            if (EXACT) {
                if (lane < 32) *(float*)(outb + eoff) = res;
            } else {
                if (lane < 32 && (t * 32 + l31) < E) *(float*)(outb + eoff) = res;
            }

            if (tn >= ntiles) break;
            t = tn; tn = tnn;
            inx = inn; fc = fcn; fr = frn;
        }
    };

    if (idx64) body(BC<true>{});
    else       body(BC<false>{});
}

extern "C" void kernel_launch(void* const* d_in, const int* in_sizes, int n_in,
                              void* d_out, int out_size, void* d_ws, size_t ws_size,
                              hipStream_t stream)
{
    const float* x  = (const float*)d_in[0];
    const void*  ei = d_in[1];
    const float* W1 = (const float*)d_in[2];
    const float* b1 = (const float*)d_in[3];
    const float* W2 = (const float*)d_in[4];
    const float* b2 = (const float*)d_in[5];
    float* out = (float*)d_out;

    const int E      = in_sizes[1] / 2;
    const int nx     = in_sizes[0];
    const int ntiles = (E + 31) / 32;

    int* flag = nullptr;
    unsigned short* xb = nullptr;
    bool use_xb = false;
    if (ws_size >= 4) flag = (int*)d_ws;
    if (ws_size >= 256 + (size_t)nx * 2) {
        xb = (unsigned short*)((char*)d_ws + 256);
        use_xb = true;
    }

    if (use_xb) {
        int nth = (nx + 3) / 4;
        prep<<<(nth + 255) / 256, 256, 0, stream>>>(x, xb, nx, (const unsigned*)ei, flag);
    } else if (flag) {
        detect_idx64<<<1, 64, 0, stream>>>((const unsigned*)ei, flag);
    }

    if ((E & 63) == 0) {
        const int npairs = E / 64;
        int blocks = 768;                      // 3072 waves
        if (npairs < blocks * 4) blocks = (npairs + 3) / 4;
        if (blocks < 1) blocks = 1;
        if (use_xb)
            edge_mlp_pair<true ><<<blocks, 256, 0, stream>>>(ei, x, xb, W1, b1, W2, b2, out, flag, E, npairs);
        else
            edge_mlp_pair<false><<<blocks, 256, 0, stream>>>(ei, x, xb, W1, b1, W2, b2, out, flag, E, npairs);
    } else {
        const bool exact = (E % 32) == 0;
        int blocks = 1250;
        if (ntiles < blocks * 4) blocks = (ntiles + 3) / 4;
        if (blocks < 1) blocks = 1;
        if (use_xb) {
            if (exact) edge_mlp1<true , true ><<<blocks, 256, 0, stream>>>(ei, x, xb, W1, b1, W2, b2, out, flag, E, ntiles);
            else       edge_mlp1<true , false><<<blocks, 256, 0, stream>>>(ei, x, xb, W1, b1, W2, b2, out, flag, E, ntiles);
        } else {
            if (exact) edge_mlp1<false, true ><<<blocks, 256, 0, stream>>>(ei, x, xb, W1, b1, W2, b2, out, flag, E, ntiles);
            else       edge_mlp1<false, false><<<blocks, 256, 0, stream>>>(ei, x, xb, W1, b1, W2, b2, out, flag, E, ntiles);
        }
    }
}

// Round 10
// 78.464 us; speedup vs baseline: 1.0374x; 1.0374x over previous
//
#include <hip/hip_runtime.h>

// EdgeNetwork: out[e] = sigmoid( tanh( [x[col[e]], x[row[e]]] @ W1 + b1 ) @ W2 + b2 )
// E = 3.2M, IN=16, HID=64.
//
// R10 (base = R8; R9's asm-pk REVERTED after +35% regression from marshaling):
//  - Measured model: v_exp_f32/v_rcp_f32 issue ~16cy/wave-op -> R8's epilogue
//    is ~80% trans cost. Replace exp-tanh with Pade(7,6) rational tanh written
//    in PLAIN f32x2 ext_vector arithmetic (+ __builtin_elementwise_fma) so
//    LLVM can select v_pk_fma_f32/v_pk_mul_f32 itself (no inline asm, no
//    marshaling). Trans per pair: 82 -> 18 (16 rcp + sigmoid).
//  - No clamp: data |h|max ~ 6.3 (Pade err <= 7e-4, well under the 1.95e-2
//    threshold; current absmax 3.9e-3 has 5x headroom).
//  - Quad common-denominator combine kept: 1 v_rcp per 4 h.
// Carried from R8: 32-edge mfma_32x32x16 swapped-operand tiles, pair-unroll
// (64 edges/iter), select-before-reduce single shfl, coalesced 64-lane store,
// 32-bit addressing, 2-deep prefetch, asm exp2/rcp only for the sigmoid.

typedef __attribute__((ext_vector_type(8)))  short bf16x8;
typedef __attribute__((ext_vector_type(2)))  float f32x2;
typedef __attribute__((ext_vector_type(4)))  float f32x4;
typedef __attribute__((ext_vector_type(16))) float f32x16;
typedef __attribute__((ext_vector_type(4)))  unsigned short u16x4;

#define LOG2E 1.4426950408889634f

__device__ __forceinline__ float asm_exp2(float x) {
    float r;
    asm("v_exp_f32 %0, %1" : "=v"(r) : "v"(x));
    return r;
}
__device__ __forceinline__ float asm_rcp(float x) {
    float r;
    asm("v_rcp_f32 %0, %1" : "=v"(r) : "v"(x));
    return r;
}

#if defined(__has_builtin)
#if __has_builtin(__builtin_elementwise_fma)
#define VFMA(a, b, c) __builtin_elementwise_fma((a), (b), (c))
#endif
#endif
#ifndef VFMA
#define VFMA(a, b, c) ((a) * (b) + (c))
#endif

template <bool B> struct BC { static constexpr bool value = B; };

__device__ __forceinline__ unsigned short f2bf(float f) {
    unsigned u = __float_as_uint(f);
    u += 0x7fffu + ((u >> 16) & 1u);
    return (unsigned short)(u >> 16);
}

// ---- x fp32 -> bf16, plus edge_index dtype detection (block 0, wave 0) ----
__global__ void prep(const float* __restrict__ x, unsigned short* __restrict__ xb, int n,
                     const unsigned* __restrict__ ei, int* __restrict__ flag) {
    if (blockIdx.x == 0 && threadIdx.x < 64) {
        unsigned v = ei[2 * threadIdx.x + 1];          // odd 32-bit words
        unsigned long long nz = __ballot(v != 0u);
        if (threadIdx.x == 0) flag[0] = (nz == 0ull) ? 1 : 0;
    }
    int i = (blockIdx.x * blockDim.x + threadIdx.x) * 4;
    if (i >= n) return;
    f32x4 v = *(const f32x4*)(x + i);
    u16x4 o;
    o[0] = f2bf(v[0]); o[1] = f2bf(v[1]); o[2] = f2bf(v[2]); o[3] = f2bf(v[3]);
    *(u16x4*)(xb + i) = o;
}

__global__ void detect_idx64(const unsigned* __restrict__ ei, int* __restrict__ flag) {
    unsigned v = ei[2 * threadIdx.x + 1];
    unsigned long long nz = __ballot(v != 0u);
    if (threadIdx.x == 0) flag[0] = (nz == 0ull) ? 1 : 0;
}

struct IdxPair { int c, r; };

// Pade(7,6) tanh coefficients (shared num/den c0).
#define PC0 135135.0f
#define PC1 17325.0f
#define PC2 378.0f
#define PD1 62370.0f
#define PD2 3150.0f
#define PD3 28.0f

// ===================== pair kernel (E % 64 == 0) =====================
template <bool USE_XB>
__global__ void __launch_bounds__(256)
edge_mlp_pair(const void* __restrict__ ei,
              const float* __restrict__ x,
              const unsigned short* __restrict__ xb,
              const float* __restrict__ W1,
              const float* __restrict__ b1,
              const float* __restrict__ W2,
              const float* __restrict__ b2,
              float* __restrict__ out,
              const int* __restrict__ flag,
              int E, int npairs)
{
    const int lane = threadIdx.x & 63;
    const int l31  = lane & 31;
    const int g    = lane >> 5;
    const int gwave  = blockIdx.x * (blockDim.x >> 6) + (threadIdx.x >> 6);
    const int nwaves = gridDim.x * (blockDim.x >> 6);

    const int idx64 = flag ? flag[0] : 0;

    // A-fragments of W1T (unscaled)
    bf16x8 w1f00, w1f01, w1f10, w1f11;
    {
        union { bf16x8 v; unsigned short u[8]; } t00, t01, t10, t11;
#pragma unroll
        for (int b = 0; b < 8; ++b) {
            int k0 = 8 * g + b;
            t00.u[b] = f2bf(W1[(k0)      * 64 + l31]);
            t01.u[b] = f2bf(W1[(16 + k0) * 64 + l31]);
            t10.u[b] = f2bf(W1[(k0)      * 64 + 32 + l31]);
            t11.u[b] = f2bf(W1[(16 + k0) * 64 + 32 + l31]);
        }
        w1f00 = t00.v; w1f01 = t01.v; w1f10 = t10.v; w1f11 = t11.v;
    }

    // Per-lane (b1, W2) register pairs: acc elements (2m, 2m+1) of hid block blk
    // map to rows rowv(2m), rowv(2m)+1.
    f32x2 b1p[16], w2p[16];
#pragma unroll
    for (int blk = 0; blk < 2; ++blk) {
#pragma unroll
        for (int m = 0; m < 8; ++m) {
            int j = 2 * m;
            int rowv = (j & 3) + 8 * (j >> 2) + 4 * g;
            int h0 = blk * 32 + rowv;
            b1p[blk * 8 + m] = f32x2{ b1[h0], b1[h0 + 1] };
            w2p[blk * 8 + m] = f32x2{ W2[h0], W2[h0 + 1] };
        }
    }
    const float bias2 = b2[0];

    const f32x2 c0v = { PC0, PC0 };
    const f32x2 c1v = { PC1, PC1 };
    const f32x2 c2v = { PC2, PC2 };
    const f32x2 d1v = { PD1, PD1 };
    const f32x2 d2v = { PD2, PD2 };
    const f32x2 d3v = { PD3, PD3 };

    const char* xbb  = (const char*)xb;
    const char* outb = (char*)out;
    const unsigned g16 = (unsigned)g << 4;

    auto body = [&](auto bc) {
        constexpr bool IDX64 = decltype(bc)::value;
        const unsigned sh = IDX64 ? 3u : 2u;
        const char* eiR = (const char*)ei;
        const char* eiC = (const char*)ei + ((size_t)E << sh);

        auto load_idx4 = [&](int pp, IdxPair& a, IdxPair& b) {
            unsigned base  = (((unsigned)pp << 6) + (unsigned)l31) << sh;
            unsigned baseB = base + (32u << sh);
            a.r = *(const int*)(eiR + base);
            a.c = *(const int*)(eiC + base);
            b.r = *(const int*)(eiR + baseB);
            b.c = *(const int*)(eiC + baseB);
        };
        auto gather = [&](int node) -> bf16x8 {
            if (USE_XB) {
                unsigned off = ((unsigned)node << 5) + g16;
                return *(const bf16x8*)(xbb + off);
            } else {
                const float* px = x + (size_t)node * 16 + 8 * g;
                f32x4 v0 = *(const f32x4*)px;
                f32x4 v1 = *(const f32x4*)(px + 4);
                union { bf16x8 v; unsigned short u[8]; } t;
#pragma unroll
                for (int b = 0; b < 4; ++b) { t.u[b] = f2bf(v0[b]); t.u[b + 4] = f2bf(v1[b]); }
                return t.v;
            }
        };

        // quad: p += sum over 4 h of w2*tanh(h+b1); Pade(7,6) in f32x2 vector
        // arithmetic (compiler-selected v_pk_*), 1 v_rcp per quad.
        auto quad = [&](const f32x16& A, int j0, int mb, float& p) {
            f32x2 hA = f32x2{ A[j0],     A[j0 + 1] } + b1p[mb];
            f32x2 hB = f32x2{ A[j0 + 2], A[j0 + 3] } + b1p[mb + 1];
            f32x2 sA = hA * hA;
            f32x2 sB = hB * hB;
            f32x2 nA = sA + c2v;
            nA = VFMA(sA, nA, c1v);
            nA = VFMA(sA, nA, c0v);
            f32x2 nB = sB + c2v;
            nB = VFMA(sB, nB, c1v);
            nB = VFMA(sB, nB, c0v);
            f32x2 dA = VFMA(sA, d3v, d2v);
            dA = VFMA(sA, dA, d1v);
            dA = VFMA(sA, dA, c0v);
            f32x2 dB = VFMA(sB, d3v, d2v);
            dB = VFMA(sB, dB, d1v);
            dB = VFMA(sB, dB, c0v);
            f32x2 numA = (w2p[mb]     * hA) * nA;
            f32x2 numB = (w2p[mb + 1] * hB) * nB;
            float D01 = dA[0] * dA[1];
            float D23 = dB[0] * dB[1];
            float N01 = fmaf(numA[0], dA[1], numA[1] * dA[0]);
            float N23 = fmaf(numB[0], dB[1], numB[1] * dB[0]);
            float N   = fmaf(N01, D23, N23 * D01);
            float P   = D01 * D23;
            p = fmaf(N, asm_rcp(P), p);
        };

        int pp = gwave;
        if (pp >= npairs) return;
        IdxPair iA, iB;
        load_idx4(pp, iA, iB);
        bf16x8 fcA = gather(iA.c), frA = gather(iA.r);
        bf16x8 fcB = gather(iB.c), frB = gather(iB.r);
        int pn = pp + nwaves;
        IdxPair iAn, iBn;
        load_idx4(pn < npairs ? pn : npairs - 1, iAn, iBn);

        const f32x16 ZC = 0.0f;

        while (true) {
            // prefetch: gathers for pair+1, indices for pair+2
            bf16x8 fcAn = gather(iAn.c), frAn = gather(iAn.r);
            bf16x8 fcBn = gather(iBn.c), frBn = gather(iBn.r);
            int pnn = pn + nwaves;
            IdxPair iAnn, iBnn;
            load_idx4(pnn < npairs ? pnn : npairs - 1, iAnn, iBnn);

            // ---- tile A ----
            float pA = 0.0f;
            {
                f32x16 a0 = __builtin_amdgcn_mfma_f32_32x32x16_bf16(w1f00, fcA, ZC, 0, 0, 0);
                a0        = __builtin_amdgcn_mfma_f32_32x32x16_bf16(w1f01, frA, a0, 0, 0, 0);
                f32x16 a1 = __builtin_amdgcn_mfma_f32_32x32x16_bf16(w1f10, fcA, ZC, 0, 0, 0);
                a1        = __builtin_amdgcn_mfma_f32_32x32x16_bf16(w1f11, frA, a1, 0, 0, 0);
#pragma unroll
                for (int q = 0; q < 4; ++q) quad(a0, q * 4, 2 * q,     pA);
#pragma unroll
                for (int q = 0; q < 4; ++q) quad(a1, q * 4, 8 + 2 * q, pA);
            }
            // ---- tile B ----
            float pB = 0.0f;
            {
                f32x16 a0 = __builtin_amdgcn_mfma_f32_32x32x16_bf16(w1f00, fcB, ZC, 0, 0, 0);
                a0        = __builtin_amdgcn_mfma_f32_32x32x16_bf16(w1f01, frB, a0, 0, 0, 0);
                f32x16 a1 = __builtin_amdgcn_mfma_f32_32x32x16_bf16(w1f10, fcB, ZC, 0, 0, 0);
                a1        = __builtin_amdgcn_mfma_f32_32x32x16_bf16(w1f11, frB, a1, 0, 0, 0);
#pragma unroll
                for (int q = 0; q < 4; ++q) quad(a0, q * 4, 2 * q,     pB);
#pragma unroll
                for (int q = 0; q < 4; ++q) quad(a1, q * 4, 8 + 2 * q, pB);
            }

            // select-before-reduce: lane's own tile partial + cross partial from lane^32
            float own   = g ? pB : pA;
            float cross = g ? pA : pB;
            own += __shfl_xor(cross, 32);
            float z = own + bias2;
            float res = asm_rcp(1.0f + asm_exp2(-z * LOG2E));

            // e = pp*64 + lane: one unpredicated, fully-coalesced 256B store
            unsigned eoff = (((unsigned)pp << 6) + (unsigned)lane) << 2;
            *(float*)(outb + eoff) = res;

            if (pn >= npairs) break;
            pp = pn; pn = pnn;
            iAn = iAnn; iBn = iBnn;
            fcA = fcAn; frA = frAn; fcB = fcBn; frB = frBn;
        }
    };

    if (idx64) body(BC<true>{});
    else       body(BC<false>{});
}

// ===================== fallback single-tile kernel (E % 64 != 0) =====================
template <bool USE_XB, bool EXACT>
__global__ void __launch_bounds__(256)
edge_mlp1(const void* __restrict__ ei,
          const float* __restrict__ x,
          const unsigned short* __restrict__ xb,
          const float* __restrict__ W1,
          const float* __restrict__ b1,
          const float* __restrict__ W2,
          const float* __restrict__ b2,
          float* __restrict__ out,
          const int* __restrict__ flag,
          int E, int ntiles)
{
    const int lane = threadIdx.x & 63;
    const int l31  = lane & 31;
    const int g    = lane >> 5;
    const int gwave  = blockIdx.x * (blockDim.x >> 6) + (threadIdx.x >> 6);
    const int nwaves = gridDim.x * (blockDim.x >> 6);

    const int idx64 = flag ? flag[0] : 0;

    bf16x8 w1f00, w1f01, w1f10, w1f11;
    {
        union { bf16x8 v; unsigned short u[8]; } t00, t01, t10, t11;
#pragma unroll
        for (int b = 0; b < 8; ++b) {
            int k0 = 8 * g + b;
            t00.u[b] = f2bf(W1[(k0)      * 64 + l31]);
            t01.u[b] = f2bf(W1[(16 + k0) * 64 + l31]);
            t10.u[b] = f2bf(W1[(k0)      * 64 + 32 + l31]);
            t11.u[b] = f2bf(W1[(16 + k0) * 64 + 32 + l31]);
        }
        w1f00 = t00.v; w1f01 = t01.v; w1f10 = t10.v; w1f11 = t11.v;
    }

    f32x2 b1p[16], w2p[16];
#pragma unroll
    for (int blk = 0; blk < 2; ++blk) {
#pragma unroll
        for (int m = 0; m < 8; ++m) {
            int j = 2 * m;
            int rowv = (j & 3) + 8 * (j >> 2) + 4 * g;
            int h0 = blk * 32 + rowv;
            b1p[blk * 8 + m] = f32x2{ b1[h0], b1[h0 + 1] };
            w2p[blk * 8 + m] = f32x2{ W2[h0], W2[h0 + 1] };
        }
    }
    const float bias2 = b2[0];

    const f32x2 c0v = { PC0, PC0 };
    const f32x2 c1v = { PC1, PC1 };
    const f32x2 c2v = { PC2, PC2 };
    const f32x2 d1v = { PD1, PD1 };
    const f32x2 d2v = { PD2, PD2 };
    const f32x2 d3v = { PD3, PD3 };

    const char* xbb  = (const char*)xb;
    const char* outb = (char*)out;
    const unsigned g16 = (unsigned)g << 4;

    auto body = [&](auto bc) {
        constexpr bool IDX64 = decltype(bc)::value;
        const unsigned sh = IDX64 ? 3u : 2u;
        const char* eiR = (const char*)ei;
        const char* eiC = (const char*)ei + ((size_t)E << sh);

        auto load_idx = [&](int tt) -> IdxPair {
            int e = tt * 32 + l31;
            unsigned ec;
            if (EXACT) ec = (unsigned)e;
            else       ec = (unsigned)(e < E ? e : E - 1);
            unsigned off = ec << sh;
            IdxPair ip;
            ip.r = *(const int*)(eiR + off);
            ip.c = *(const int*)(eiC + off);
            return ip;
        };
        auto gather = [&](int node) -> bf16x8 {
            if (USE_XB) {
                unsigned off = ((unsigned)node << 5) + g16;
                return *(const bf16x8*)(xbb + off);
            } else {
                const float* px = x + (size_t)node * 16 + 8 * g;
                f32x4 v0 = *(const f32x4*)px;
                f32x4 v1 = *(const f32x4*)(px + 4);
                union { bf16x8 v; unsigned short u[8]; } t;
#pragma unroll
                for (int b = 0; b < 4; ++b) { t.u[b] = f2bf(v0[b]); t.u[b + 4] = f2bf(v1[b]); }
                return t.v;
            }
        };

        auto quad = [&](const f32x16& A, int j0, int mb, float& p) {
            f32x2 hA = f32x2{ A[j0],     A[j0 + 1] } + b1p[mb];
            f32x2 hB = f32x2{ A[j0 + 2], A[j0 + 3] } + b1p[mb + 1];
            f32x2 sA = hA * hA;
            f32x2 sB = hB * hB;
            f32x2 nA = sA + c2v;
            nA = VFMA(sA, nA, c1v);
            nA = VFMA(sA, nA, c0v);
            f32x2 nB = sB + c2v;
            nB = VFMA(sB, nB, c1v);
            nB = VFMA(sB, nB, c0v);
            f32x2 dA = VFMA(sA, d3v, d2v);
            dA = VFMA(sA, dA, d1v);
            dA = VFMA(sA, dA, c0v);
            f32x2 dB = VFMA(sB, d3v, d2v);
            dB = VFMA(sB, dB, d1v);
            dB = VFMA(sB, dB, c0v);
            f32x2 numA = (w2p[mb]     * hA) * nA;
            f32x2 numB = (w2p[mb + 1] * hB) * nB;
            float D01 = dA[0] * dA[1];
            float D23 = dB[0] * dB[1];
            float N01 = fmaf(numA[0], dA[1], numA[1] * dA[0]);
            float N23 = fmaf(numB[0], dB[1], numB[1] * dB[0]);
            float N   = fmaf(N01, D23, N23 * D01);
            float P   = D01 * D23;
            p = fmaf(N, asm_rcp(P), p);
        };

        int t = gwave;
        if (t >= ntiles) return;
        IdxPair ic = load_idx(t);
        bf16x8 fc = gather(ic.c);
        bf16x8 fr = gather(ic.r);
        int tn = t + nwaves;
        IdxPair inx = load_idx(tn < ntiles ? tn : ntiles - 1);

        const f32x16 ZC = 0.0f;

        while (true) {
            bf16x8 fcn = gather(inx.c);
            bf16x8 frn = gather(inx.r);
            int tnn = tn + nwaves;
            IdxPair inn = load_idx(tnn < ntiles ? tnn : ntiles - 1);

            f32x16 acc0 = __builtin_amdgcn_mfma_f32_32x32x16_bf16(w1f00, fc, ZC, 0, 0, 0);
            acc0        = __builtin_amdgcn_mfma_f32_32x32x16_bf16(w1f01, fr, acc0, 0, 0, 0);
            f32x16 acc1 = __builtin_amdgcn_mfma_f32_32x32x16_bf16(w1f10, fc, ZC, 0, 0, 0);
            acc1        = __builtin_amdgcn_mfma_f32_32x32x16_bf16(w1f11, fr, acc1, 0, 0, 0);

            float p = 0.0f;
#pragma unroll
            for (int q = 0; q < 4; ++q) quad(acc0, q * 4, 2 * q,     p);
#pragma unroll
            for (int q = 0; q < 4; ++q) quad(acc1, q * 4, 8 + 2 * q, p);

            p += __shfl_xor(p, 32);
            float z = p + bias2;
            float res = asm_rcp(1.0f + asm_exp2(-z * LOG2E));

            unsigned eoff = ((unsigned)(t * 32 + l31)) << 2;
            if (EXACT) {
                if (lane < 32) *(float*)(outb + eoff) = res;
            } else {
                if (lane < 32 && (t * 32 + l31) < E) *(float*)(outb + eoff) = res;
            }

            if (tn >= ntiles) break;
            t = tn; tn = tnn;
            inx = inn; fc = fcn; fr = frn;
        }
    };

    if (idx64) body(BC<true>{});
    else       body(BC<false>{});
}

extern "C" void kernel_launch(void* const* d_in, const int* in_sizes, int n_in,
                              void* d_out, int out_size, void* d_ws, size_t ws_size,
                              hipStream_t stream)
{
    const float* x  = (const float*)d_in[0];
    const void*  ei = d_in[1];
    const float* W1 = (const float*)d_in[2];
    const float* b1 = (const float*)d_in[3];
    const float* W2 = (const float*)d_in[4];
    const float* b2 = (const float*)d_in[5];
    float* out = (float*)d_out;

    const int E      = in_sizes[1] / 2;
    const int nx     = in_sizes[0];
    const int ntiles = (E + 31) / 32;

    int* flag = nullptr;
    unsigned short* xb = nullptr;
    bool use_xb = false;
    if (ws_size >= 4) flag = (int*)d_ws;
    if (ws_size >= 256 + (size_t)nx * 2) {
        xb = (unsigned short*)((char*)d_ws + 256);
        use_xb = true;
    }

    if (use_xb) {
        int nth = (nx + 3) / 4;
        prep<<<(nth + 255) / 256, 256, 0, stream>>>(x, xb, nx, (const unsigned*)ei, flag);
    } else if (flag) {
        detect_idx64<<<1, 64, 0, stream>>>((const unsigned*)ei, flag);
    }

    if ((E & 63) == 0) {
        const int npairs = E / 64;
        int blocks = 768;                      // 3072 waves
        if (npairs < blocks * 4) blocks = (npairs + 3) / 4;
        if (blocks < 1) blocks = 1;
        if (use_xb)
            edge_mlp_pair<true ><<<blocks, 256, 0, stream>>>(ei, x, xb, W1, b1, W2, b2, out, flag, E, npairs);
        else
            edge_mlp_pair<false><<<blocks, 256, 0, stream>>>(ei, x, xb, W1, b1, W2, b2, out, flag, E, npairs);
    } else {
        const bool exact = (E % 32) == 0;
        int blocks = 1250;
        if (ntiles < blocks * 4) blocks = (ntiles + 3) / 4;
        if (blocks < 1) blocks = 1;
        if (use_xb) {
            if (exact) edge_mlp1<true , true ><<<blocks, 256, 0, stream>>>(ei, x, xb, W1, b1, W2, b2, out, flag, E, ntiles);
            else       edge_mlp1<true , false><<<blocks, 256, 0, stream>>>(ei, x, xb, W1, b1, W2, b2, out, flag, E, ntiles);
        } else {
            if (exact) edge_mlp1<false, true ><<<blocks, 256, 0, stream>>>(ei, x, xb, W1, b1, W2, b2, out, flag, E, ntiles);
            else       edge_mlp1<false, false><<<blocks, 256, 0, stream>>>(ei, x, xb, W1, b1, W2, b2, out, flag, E, ntiles);
        }
    }
}

// Round 11
// 62.663 us; speedup vs baseline: 1.2990x; 1.2522x over previous
//
#include <hip/hip_runtime.h>

// EdgeNetwork: out[e] = sigmoid( tanh( [x[col[e]], x[row[e]]] @ W1 + b1 ) @ W2 + b2 )
// E = 3.2M, IN=16, HID=64.
//
// R11 = R8 RESTORED (best: 60.3us). R9 (asm pk) and R10 (vector-IR pk) both
// regressed -- hipcc neither preserves nor forms v_pk_*_f32; scalar Pade is
// worse than exp-tanh. Single change vs R8: pair grid 768 -> 1250 blocks
// (5000 waves x exactly 10 pairs; removes the 16.3-pairs/wave ragged tail).
//
// Structure: 32-edge mfma_32x32x16 swapped-operand tiles, pair-unroll (64
// edges/iter), exp-based tanh folded as rcp(fma(eb, exp2(acc), 1)) with
// quad common-denominator (1 rcp / 4 h), (eb,-2w2) consts staged via LDS then
// hoisted to 16 float4 regs, select-before-reduce single shfl, coalesced
// 64-lane store, 32-bit addressing, 2-deep prefetch, asm exp2/rcp.

typedef __attribute__((ext_vector_type(8)))  short bf16x8;
typedef __attribute__((ext_vector_type(4)))  float f32x4;
typedef __attribute__((ext_vector_type(16))) float f32x16;
typedef __attribute__((ext_vector_type(4)))  unsigned short u16x4;

#define LOG2E 1.4426950408889634f

__device__ __forceinline__ float asm_exp2(float x) {
    float r;
    asm("v_exp_f32 %0, %1" : "=v"(r) : "v"(x));
    return r;
}
__device__ __forceinline__ float asm_rcp(float x) {
    float r;
    asm("v_rcp_f32 %0, %1" : "=v"(r) : "v"(x));
    return r;
}

template <bool B> struct BC { static constexpr bool value = B; };

__device__ __forceinline__ unsigned short f2bf(float f) {
    unsigned u = __float_as_uint(f);
    u += 0x7fffu + ((u >> 16) & 1u);
    return (unsigned short)(u >> 16);
}

// ---- x fp32 -> bf16, plus edge_index dtype detection (block 0, wave 0) ----
__global__ void prep(const float* __restrict__ x, unsigned short* __restrict__ xb, int n,
                     const unsigned* __restrict__ ei, int* __restrict__ flag) {
    if (blockIdx.x == 0 && threadIdx.x < 64) {
        unsigned v = ei[2 * threadIdx.x + 1];          // odd 32-bit words
        unsigned long long nz = __ballot(v != 0u);
        if (threadIdx.x == 0) flag[0] = (nz == 0ull) ? 1 : 0;
    }
    int i = (blockIdx.x * blockDim.x + threadIdx.x) * 4;
    if (i >= n) return;
    f32x4 v = *(const f32x4*)(x + i);
    u16x4 o;
    o[0] = f2bf(v[0]); o[1] = f2bf(v[1]); o[2] = f2bf(v[2]); o[3] = f2bf(v[3]);
    *(u16x4*)(xb + i) = o;
}

__global__ void detect_idx64(const unsigned* __restrict__ ei, int* __restrict__ flag) {
    unsigned v = ei[2 * threadIdx.x + 1];
    unsigned long long nz = __ballot(v != 0u);
    if (threadIdx.x == 0) flag[0] = (nz == 0ull) ? 1 : 0;
}

struct IdxPair { int c, r; };

// ===================== pair kernel (E % 64 == 0) =====================
template <bool USE_XB>
__global__ void __launch_bounds__(256)
edge_mlp_pair(const void* __restrict__ ei,
              const float* __restrict__ x,
              const unsigned short* __restrict__ xb,
              const float* __restrict__ W1,
              const float* __restrict__ b1,
              const float* __restrict__ W2,
              const float* __restrict__ b2,
              float* __restrict__ out,
              const int* __restrict__ flag,
              int E, int npairs)
{
    __shared__ float2 tbl[64];   // staging only; loop uses registers

    const int lane = threadIdx.x & 63;
    const int l31  = lane & 31;
    const int g    = lane >> 5;
    const int gwave  = blockIdx.x * (blockDim.x >> 6) + (threadIdx.x >> 6);
    const int nwaves = gridDim.x * (blockDim.x >> 6);

    const int idx64 = flag ? flag[0] : 0;
    const float S = 2.0f * LOG2E;

    {
        int tid = threadIdx.x;
        if (tid < 64) {
            int tg = tid >> 5, tb = (tid >> 4) & 1, tj = tid & 15;
            int rowv = (tj & 3) + 8 * (tj >> 2) + 4 * tg;
            int h = 32 * tb + rowv;
            float2 cw;
            cw.x = exp2f(S * b1[h]);
            cw.y = -2.0f * W2[h];
            tbl[tid] = cw;
        }
    }

    // A-fragments of S*W1T
    bf16x8 w1f00, w1f01, w1f10, w1f11;
    {
        union { bf16x8 v; unsigned short u[8]; } t00, t01, t10, t11;
#pragma unroll
        for (int b = 0; b < 8; ++b) {
            int k0 = 8 * g + b;
            t00.u[b] = f2bf(S * W1[(k0)      * 64 + l31]);
            t01.u[b] = f2bf(S * W1[(16 + k0) * 64 + l31]);
            t10.u[b] = f2bf(S * W1[(k0)      * 64 + 32 + l31]);
            t11.u[b] = f2bf(S * W1[(16 + k0) * 64 + 32 + l31]);
        }
        w1f00 = t00.v; w1f01 = t01.v; w1f10 = t10.v; w1f11 = t11.v;
    }

    float pbase = 0.f;
#pragma unroll
    for (int j = 0; j < 16; ++j) {
        int rowv = (j & 3) + 8 * (j >> 2) + 4 * g;
        pbase += W2[rowv] + W2[32 + rowv];
    }
    const float bias2 = b2[0];

    __syncthreads();

    // Hoist the whole per-lane constant table into registers (loop-invariant).
    float4 cc[16];
    {
        const float4* t4 = (const float4*)(&tbl[g * 32]);
#pragma unroll
        for (int j = 0; j < 16; ++j) cc[j] = t4[j];
    }

    const char* xbb  = (const char*)xb;
    const char* outb = (char*)out;
    const unsigned g16 = (unsigned)g << 4;

    auto body = [&](auto bc) {
        constexpr bool IDX64 = decltype(bc)::value;
        const unsigned sh = IDX64 ? 3u : 2u;
        const char* eiR = (const char*)ei;
        const char* eiC = (const char*)ei + ((size_t)E << sh);

        auto load_idx4 = [&](int pp, IdxPair& a, IdxPair& b) {
            unsigned base  = (((unsigned)pp << 6) + (unsigned)l31) << sh;
            unsigned baseB = base + (32u << sh);
            a.r = *(const int*)(eiR + base);
            a.c = *(const int*)(eiC + base);
            b.r = *(const int*)(eiR + baseB);
            b.c = *(const int*)(eiC + baseB);
        };
        auto gather = [&](int node) -> bf16x8 {
            if (USE_XB) {
                unsigned off = ((unsigned)node << 5) + g16;
                return *(const bf16x8*)(xbb + off);
            } else {
                const float* px = x + (size_t)node * 16 + 8 * g;
                f32x4 v0 = *(const f32x4*)px;
                f32x4 v1 = *(const f32x4*)(px + 4);
                union { bf16x8 v; unsigned short u[8]; } t;
#pragma unroll
                for (int b = 0; b < 4; ++b) { t.u[b] = f2bf(v0[b]); t.u[b + 4] = f2bf(v1[b]); }
                return t.v;
            }
        };

        auto quad = [&](const f32x16& A, int k, float4 c01, float4 c23, float& p) {
            float E0 = asm_exp2(A[k]);
            float E1 = asm_exp2(A[k + 1]);
            float E2 = asm_exp2(A[k + 2]);
            float E3 = asm_exp2(A[k + 3]);
            float D0 = fmaf(c01.x, E0, 1.0f);
            float D1 = fmaf(c01.z, E1, 1.0f);
            float D2 = fmaf(c23.x, E2, 1.0f);
            float D3 = fmaf(c23.z, E3, 1.0f);
            float D01 = D0 * D1;
            float D23 = D2 * D3;
            float N01 = fmaf(c01.y, D1, c01.w * D0);
            float N23 = fmaf(c23.y, D3, c23.w * D2);
            float N   = fmaf(N01, D23, N23 * D01);
            float P   = D01 * D23;
            p = fmaf(N, asm_rcp(P), p);
        };

        int pp = gwave;
        if (pp >= npairs) return;
        IdxPair iA, iB;
        load_idx4(pp, iA, iB);
        bf16x8 fcA = gather(iA.c), frA = gather(iA.r);
        bf16x8 fcB = gather(iB.c), frB = gather(iB.r);
        int pn = pp + nwaves;
        IdxPair iAn, iBn;
        load_idx4(pn < npairs ? pn : npairs - 1, iAn, iBn);

        const f32x16 ZC = 0.0f;

        while (true) {
            // prefetch: gathers for pair+1, indices for pair+2
            bf16x8 fcAn = gather(iAn.c), frAn = gather(iAn.r);
            bf16x8 fcBn = gather(iBn.c), frBn = gather(iBn.r);
            int pnn = pn + nwaves;
            IdxPair iAnn, iBnn;
            load_idx4(pnn < npairs ? pnn : npairs - 1, iAnn, iBnn);

            // ---- tile A ----
            float pA = pbase;
            {
                f32x16 a0 = __builtin_amdgcn_mfma_f32_32x32x16_bf16(w1f00, fcA, ZC, 0, 0, 0);
                a0        = __builtin_amdgcn_mfma_f32_32x32x16_bf16(w1f01, frA, a0, 0, 0, 0);
                f32x16 a1 = __builtin_amdgcn_mfma_f32_32x32x16_bf16(w1f10, fcA, ZC, 0, 0, 0);
                a1        = __builtin_amdgcn_mfma_f32_32x32x16_bf16(w1f11, frA, a1, 0, 0, 0);
#pragma unroll
                for (int q = 0; q < 4; ++q) quad(a0, q * 4, cc[2 * q],     cc[2 * q + 1], pA);
#pragma unroll
                for (int q = 0; q < 4; ++q) quad(a1, q * 4, cc[8 + 2 * q], cc[9 + 2 * q], pA);
            }
            // ---- tile B ----
            float pB = pbase;
            {
                f32x16 a0 = __builtin_amdgcn_mfma_f32_32x32x16_bf16(w1f00, fcB, ZC, 0, 0, 0);
                a0        = __builtin_amdgcn_mfma_f32_32x32x16_bf16(w1f01, frB, a0, 0, 0, 0);
                f32x16 a1 = __builtin_amdgcn_mfma_f32_32x32x16_bf16(w1f10, fcB, ZC, 0, 0, 0);
                a1        = __builtin_amdgcn_mfma_f32_32x32x16_bf16(w1f11, frB, a1, 0, 0, 0);
#pragma unroll
                for (int q = 0; q < 4; ++q) quad(a0, q * 4, cc[2 * q],     cc[2 * q + 1], pB);
#pragma unroll
                for (int q = 0; q < 4; ++q) quad(a1, q * 4, cc[8 + 2 * q], cc[9 + 2 * q], pB);
            }

            // select-before-reduce: lane's own tile partial + cross partial from lane^32
            float own   = g ? pB : pA;
            float cross = g ? pA : pB;
            own += __shfl_xor(cross, 32);
            float z = own + bias2;
            float res = asm_rcp(1.0f + asm_exp2(-z * LOG2E));

            // e = pp*64 + lane: one unpredicated, fully-coalesced 256B store
            unsigned eoff = (((unsigned)pp << 6) + (unsigned)lane) << 2;
            *(float*)(outb + eoff) = res;

            if (pn >= npairs) break;
            pp = pn; pn = pnn;
            iAn = iAnn; iBn = iBnn;
            fcA = fcAn; frA = frAn; fcB = fcBn; frB = frBn;
        }
    };

    if (idx64) body(BC<true>{});
    else       body(BC<false>{});
}

// ===================== fallback single-tile kernel (E % 64 != 0) =====================
template <bool USE_XB, bool EXACT>
__global__ void __launch_bounds__(256)
edge_mlp1(const void* __restrict__ ei,
          const float* __restrict__ x,
          const unsigned short* __restrict__ xb,
          const float* __restrict__ W1,
          const float* __restrict__ b1,
          const float* __restrict__ W2,
          const float* __restrict__ b2,
          float* __restrict__ out,
          const int* __restrict__ flag,
          int E, int ntiles)
{
    __shared__ float2 tbl[64];

    const int lane = threadIdx.x & 63;
    const int l31  = lane & 31;
    const int g    = lane >> 5;
    const int gwave  = blockIdx.x * (blockDim.x >> 6) + (threadIdx.x >> 6);
    const int nwaves = gridDim.x * (blockDim.x >> 6);

    const int idx64 = flag ? flag[0] : 0;
    const float S = 2.0f * LOG2E;

    {
        int tid = threadIdx.x;
        if (tid < 64) {
            int tg = tid >> 5, tb = (tid >> 4) & 1, tj = tid & 15;
            int rowv = (tj & 3) + 8 * (tj >> 2) + 4 * tg;
            int h = 32 * tb + rowv;
            float2 cw;
            cw.x = exp2f(S * b1[h]);
            cw.y = -2.0f * W2[h];
            tbl[tid] = cw;
        }
    }

    bf16x8 w1f00, w1f01, w1f10, w1f11;
    {
        union { bf16x8 v; unsigned short u[8]; } t00, t01, t10, t11;
#pragma unroll
        for (int b = 0; b < 8; ++b) {
            int k0 = 8 * g + b;
            t00.u[b] = f2bf(S * W1[(k0)      * 64 + l31]);
            t01.u[b] = f2bf(S * W1[(16 + k0) * 64 + l31]);
            t10.u[b] = f2bf(S * W1[(k0)      * 64 + 32 + l31]);
            t11.u[b] = f2bf(S * W1[(16 + k0) * 64 + 32 + l31]);
        }
        w1f00 = t00.v; w1f01 = t01.v; w1f10 = t10.v; w1f11 = t11.v;
    }

    float pbase = 0.f;
#pragma unroll
    for (int j = 0; j < 16; ++j) {
        int rowv = (j & 3) + 8 * (j >> 2) + 4 * g;
        pbase += W2[rowv] + W2[32 + rowv];
    }
    const float bias2 = b2[0];

    __syncthreads();
    const float4* t4 = (const float4*)(&tbl[g * 32]);

    const char* xbb  = (const char*)xb;
    const char* outb = (char*)out;
    const unsigned g16 = (unsigned)g << 4;

    auto body = [&](auto bc) {
        constexpr bool IDX64 = decltype(bc)::value;
        const unsigned sh = IDX64 ? 3u : 2u;
        const char* eiR = (const char*)ei;
        const char* eiC = (const char*)ei + ((size_t)E << sh);

        auto load_idx = [&](int tt) -> IdxPair {
            int e = tt * 32 + l31;
            unsigned ec;
            if (EXACT) ec = (unsigned)e;
            else       ec = (unsigned)(e < E ? e : E - 1);
            unsigned off = ec << sh;
            IdxPair ip;
            ip.r = *(const int*)(eiR + off);
            ip.c = *(const int*)(eiC + off);
            return ip;
        };
        auto gather = [&](int node) -> bf16x8 {
            if (USE_XB) {
                unsigned off = ((unsigned)node << 5) + g16;
                return *(const bf16x8*)(xbb + off);
            } else {
                const float* px = x + (size_t)node * 16 + 8 * g;
                f32x4 v0 = *(const f32x4*)px;
                f32x4 v1 = *(const f32x4*)(px + 4);
                union { bf16x8 v; unsigned short u[8]; } t;
#pragma unroll
                for (int b = 0; b < 4; ++b) { t.u[b] = f2bf(v0[b]); t.u[b + 4] = f2bf(v1[b]); }
                return t.v;
            }
        };

        auto quad = [&](const f32x16& A, int k, float4 c01, float4 c23, float& p) {
            float E0 = asm_exp2(A[k]);
            float E1 = asm_exp2(A[k + 1]);
            float E2 = asm_exp2(A[k + 2]);
            float E3 = asm_exp2(A[k + 3]);
            float D0 = fmaf(c01.x, E0, 1.0f);
            float D1 = fmaf(c01.z, E1, 1.0f);
            float D2 = fmaf(c23.x, E2, 1.0f);
            float D3 = fmaf(c23.z, E3, 1.0f);
            float D01 = D0 * D1;
            float D23 = D2 * D3;
            float N01 = fmaf(c01.y, D1, c01.w * D0);
            float N23 = fmaf(c23.y, D3, c23.w * D2);
            float N   = fmaf(N01, D23, N23 * D01);
            float P   = D01 * D23;
            p = fmaf(N, asm_rcp(P), p);
        };

        int t = gwave;
        if (t >= ntiles) return;
        IdxPair ic = load_idx(t);
        bf16x8 fc = gather(ic.c);
        bf16x8 fr = gather(ic.r);
        int tn = t + nwaves;
        IdxPair inx = load_idx(tn < ntiles ? tn : ntiles - 1);

        const f32x16 ZC = 0.0f;

        while (true) {
            bf16x8 fcn = gather(inx.c);
            bf16x8 frn = gather(inx.r);
            int tnn = tn + nwaves;
            IdxPair inn = load_idx(tnn < ntiles ? tnn : ntiles - 1);

            f32x16 acc0 = __builtin_amdgcn_mfma_f32_32x32x16_bf16(w1f00, fc, ZC, 0, 0, 0);
            acc0        = __builtin_amdgcn_mfma_f32_32x32x16_bf16(w1f01, fr, acc0, 0, 0, 0);
            f32x16 acc1 = __builtin_amdgcn_mfma_f32_32x32x16_bf16(w1f10, fc, ZC, 0, 0, 0);
            acc1        = __builtin_amdgcn_mfma_f32_32x32x16_bf16(w1f11, fr, acc1, 0, 0, 0);

            float p = pbase;
#pragma unroll
            for (int q = 0; q < 4; ++q) quad(acc0, q * 4, t4[2 * q],     t4[2 * q + 1], p);
#pragma unroll
            for (int q = 0; q < 4; ++q) quad(acc1, q * 4, t4[8 + 2 * q], t4[9 + 2 * q], p);

            p += __shfl_xor(p, 32);
            float z = p + bias2;
            float res = asm_rcp(1.0f + asm_exp2(-z * LOG2E));

            unsigned eoff = ((unsigned)(t * 32 + l31)) << 2;
            if (EXACT) {
                if (lane < 32) *(float*)(outb + eoff) = res;
            } else {
                if (lane < 32 && (t * 32 + l31) < E) *(float*)(outb + eoff) = res;
            }

            if (tn >= ntiles) break;
            t = tn; tn = tnn;
            inx = inn; fc = fcn; fr = frn;
        }
    };

    if (idx64) body(BC<true>{});
    else       body(BC<false>{});
}

extern "C" void kernel_launch(void* const* d_in, const int* in_sizes, int n_in,
                              void* d_out, int out_size, void* d_ws, size_t ws_size,
                              hipStream_t stream)
{
    const float* x  = (const float*)d_in[0];
    const void*  ei = d_in[1];
    const float* W1 = (const float*)d_in[2];
    const float* b1 = (const float*)d_in[3];
    const float* W2 = (const float*)d_in[4];
    const float* b2 = (const float*)d_in[5];
    float* out = (float*)d_out;

    const int E      = in_sizes[1] / 2;
    const int nx     = in_sizes[0];
    const int ntiles = (E + 31) / 32;

    int* flag = nullptr;
    unsigned short* xb = nullptr;
    bool use_xb = false;
    if (ws_size >= 4) flag = (int*)d_ws;
    if (ws_size >= 256 + (size_t)nx * 2) {
        xb = (unsigned short*)((char*)d_ws + 256);
        use_xb = true;
    }

    if (use_xb) {
        int nth = (nx + 3) / 4;
        prep<<<(nth + 255) / 256, 256, 0, stream>>>(x, xb, nx, (const unsigned*)ei, flag);
    } else if (flag) {
        detect_idx64<<<1, 64, 0, stream>>>((const unsigned*)ei, flag);
    }

    if ((E & 63) == 0) {
        const int npairs = E / 64;
        // 1250 blocks = 5000 waves: npairs=50000 -> exactly 10 pairs per wave
        int blocks = 1250;
        if (npairs < blocks * 4) blocks = (npairs + 3) / 4;
        if (blocks < 1) blocks = 1;
        if (use_xb)
            edge_mlp_pair<true ><<<blocks, 256, 0, stream>>>(ei, x, xb, W1, b1, W2, b2, out, flag, E, npairs);
        else
            edge_mlp_pair<false><<<blocks, 256, 0, stream>>>(ei, x, xb, W1, b1, W2, b2, out, flag, E, npairs);
    } else {
        const bool exact = (E % 32) == 0;
        int blocks = 1250;
        if (ntiles < blocks * 4) blocks = (ntiles + 3) / 4;
        if (blocks < 1) blocks = 1;
        if (use_xb) {
            if (exact) edge_mlp1<true , true ><<<blocks, 256, 0, stream>>>(ei, x, xb, W1, b1, W2, b2, out, flag, E, ntiles);
            else       edge_mlp1<true , false><<<blocks, 256, 0, stream>>>(ei, x, xb, W1, b1, W2, b2, out, flag, E, ntiles);
        } else {
            if (exact) edge_mlp1<false, true ><<<blocks, 256, 0, stream>>>(ei, x, xb, W1, b1, W2, b2, out, flag, E, ntiles);
            else       edge_mlp1<false, false><<<blocks, 256, 0, stream>>>(ei, x, xb, W1, b1, W2, b2, out, flag, E, ntiles);
        }
    }
}

// Round 12
// 60.413 us; speedup vs baseline: 1.3473x; 1.0372x over previous
//
#include <hip/hip_runtime.h>

// EdgeNetwork: out[e] = sigmoid( tanh( [x[col[e]], x[row[e]]] @ W1 + b1 ) @ W2 + b2 )
// E = 3.2M, IN=16, HID=64.
//
// FINAL = R8 verbatim (best measured: 60.3us, grid 768). R11's balanced grid
// (1250) measured slightly WORSE (62.7) -- kernel is TLP/grid-insensitive in
// the 3-8 wave/SIMD range; 768 blocks is the best measured point.
//
// Structure: 32-edge mfma_32x32x16 swapped-operand tiles, pair-unroll (64
// edges/iter), exp-based tanh folded as rcp(fma(eb, exp2(acc), 1)) with
// quad common-denominator (1 rcp / 4 h), (eb,-2w2) consts staged via LDS then
// hoisted to 16 float4 regs, select-before-reduce single shfl, coalesced
// 64-lane store, 32-bit addressing, 2-deep prefetch, asm exp2/rcp.
//
// Measured structural floor: 208M v_exp_f32 + 52M v_rcp_f32 on the 1/4-rate
// trans pipe (~26us occupancy) + ~14us VALU issue + ~30% scheduling idle
// that survived TLP (R5/R6/R11), trans-count (R6), pk-SIMD (R9/R10), and
// occupancy (R7) attacks. Memory: HBM ~6% of peak, FETCH ~= ideal, 0 bank
// conflicts -- not a factor.

typedef __attribute__((ext_vector_type(8)))  short bf16x8;
typedef __attribute__((ext_vector_type(4)))  float f32x4;
typedef __attribute__((ext_vector_type(16))) float f32x16;
typedef __attribute__((ext_vector_type(4)))  unsigned short u16x4;

#define LOG2E 1.4426950408889634f

__device__ __forceinline__ float asm_exp2(float x) {
    float r;
    asm("v_exp_f32 %0, %1" : "=v"(r) : "v"(x));
    return r;
}
__device__ __forceinline__ float asm_rcp(float x) {
    float r;
    asm("v_rcp_f32 %0, %1" : "=v"(r) : "v"(x));
    return r;
}

template <bool B> struct BC { static constexpr bool value = B; };

__device__ __forceinline__ unsigned short f2bf(float f) {
    unsigned u = __float_as_uint(f);
    u += 0x7fffu + ((u >> 16) & 1u);
    return (unsigned short)(u >> 16);
}

// ---- x fp32 -> bf16, plus edge_index dtype detection (block 0, wave 0) ----
__global__ void prep(const float* __restrict__ x, unsigned short* __restrict__ xb, int n,
                     const unsigned* __restrict__ ei, int* __restrict__ flag) {
    if (blockIdx.x == 0 && threadIdx.x < 64) {
        unsigned v = ei[2 * threadIdx.x + 1];          // odd 32-bit words
        unsigned long long nz = __ballot(v != 0u);
        if (threadIdx.x == 0) flag[0] = (nz == 0ull) ? 1 : 0;
    }
    int i = (blockIdx.x * blockDim.x + threadIdx.x) * 4;
    if (i >= n) return;
    f32x4 v = *(const f32x4*)(x + i);
    u16x4 o;
    o[0] = f2bf(v[0]); o[1] = f2bf(v[1]); o[2] = f2bf(v[2]); o[3] = f2bf(v[3]);
    *(u16x4*)(xb + i) = o;
}

__global__ void detect_idx64(const unsigned* __restrict__ ei, int* __restrict__ flag) {
    unsigned v = ei[2 * threadIdx.x + 1];
    unsigned long long nz = __ballot(v != 0u);
    if (threadIdx.x == 0) flag[0] = (nz == 0ull) ? 1 : 0;
}

struct IdxPair { int c, r; };

// ===================== pair kernel (E % 64 == 0) =====================
template <bool USE_XB>
__global__ void __launch_bounds__(256)
edge_mlp_pair(const void* __restrict__ ei,
              const float* __restrict__ x,
              const unsigned short* __restrict__ xb,
              const float* __restrict__ W1,
              const float* __restrict__ b1,
              const float* __restrict__ W2,
              const float* __restrict__ b2,
              float* __restrict__ out,
              const int* __restrict__ flag,
              int E, int npairs)
{
    __shared__ float2 tbl[64];   // staging only; loop uses registers

    const int lane = threadIdx.x & 63;
    const int l31  = lane & 31;
    const int g    = lane >> 5;
    const int gwave  = blockIdx.x * (blockDim.x >> 6) + (threadIdx.x >> 6);
    const int nwaves = gridDim.x * (blockDim.x >> 6);

    const int idx64 = flag ? flag[0] : 0;
    const float S = 2.0f * LOG2E;

    {
        int tid = threadIdx.x;
        if (tid < 64) {
            int tg = tid >> 5, tb = (tid >> 4) & 1, tj = tid & 15;
            int rowv = (tj & 3) + 8 * (tj >> 2) + 4 * tg;
            int h = 32 * tb + rowv;
            float2 cw;
            cw.x = exp2f(S * b1[h]);
            cw.y = -2.0f * W2[h];
            tbl[tid] = cw;
        }
    }

    // A-fragments of S*W1T
    bf16x8 w1f00, w1f01, w1f10, w1f11;
    {
        union { bf16x8 v; unsigned short u[8]; } t00, t01, t10, t11;
#pragma unroll
        for (int b = 0; b < 8; ++b) {
            int k0 = 8 * g + b;
            t00.u[b] = f2bf(S * W1[(k0)      * 64 + l31]);
            t01.u[b] = f2bf(S * W1[(16 + k0) * 64 + l31]);
            t10.u[b] = f2bf(S * W1[(k0)      * 64 + 32 + l31]);
            t11.u[b] = f2bf(S * W1[(16 + k0) * 64 + 32 + l31]);
        }
        w1f00 = t00.v; w1f01 = t01.v; w1f10 = t10.v; w1f11 = t11.v;
    }

    float pbase = 0.f;
#pragma unroll
    for (int j = 0; j < 16; ++j) {
        int rowv = (j & 3) + 8 * (j >> 2) + 4 * g;
        pbase += W2[rowv] + W2[32 + rowv];
    }
    const float bias2 = b2[0];

    __syncthreads();

    // Hoist the whole per-lane constant table into registers (loop-invariant).
    float4 cc[16];
    {
        const float4* t4 = (const float4*)(&tbl[g * 32]);
#pragma unroll
        for (int j = 0; j < 16; ++j) cc[j] = t4[j];
    }

    const char* xbb  = (const char*)xb;
    const char* outb = (char*)out;
    const unsigned g16 = (unsigned)g << 4;

    auto body = [&](auto bc) {
        constexpr bool IDX64 = decltype(bc)::value;
        const unsigned sh = IDX64 ? 3u : 2u;
        const char* eiR = (const char*)ei;
        const char* eiC = (const char*)ei + ((size_t)E << sh);

        auto load_idx4 = [&](int pp, IdxPair& a, IdxPair& b) {
            unsigned base  = (((unsigned)pp << 6) + (unsigned)l31) << sh;
            unsigned baseB = base + (32u << sh);
            a.r = *(const int*)(eiR + base);
            a.c = *(const int*)(eiC + base);
            b.r = *(const int*)(eiR + baseB);
            b.c = *(const int*)(eiC + baseB);
        };
        auto gather = [&](int node) -> bf16x8 {
            if (USE_XB) {
                unsigned off = ((unsigned)node << 5) + g16;
                return *(const bf16x8*)(xbb + off);
            } else {
                const float* px = x + (size_t)node * 16 + 8 * g;
                f32x4 v0 = *(const f32x4*)px;
                f32x4 v1 = *(const f32x4*)(px + 4);
                union { bf16x8 v; unsigned short u[8]; } t;
#pragma unroll
                for (int b = 0; b < 4; ++b) { t.u[b] = f2bf(v0[b]); t.u[b + 4] = f2bf(v1[b]); }
                return t.v;
            }
        };

        auto quad = [&](const f32x16& A, int k, float4 c01, float4 c23, float& p) {
            float E0 = asm_exp2(A[k]);
            float E1 = asm_exp2(A[k + 1]);
            float E2 = asm_exp2(A[k + 2]);
            float E3 = asm_exp2(A[k + 3]);
            float D0 = fmaf(c01.x, E0, 1.0f);
            float D1 = fmaf(c01.z, E1, 1.0f);
            float D2 = fmaf(c23.x, E2, 1.0f);
            float D3 = fmaf(c23.z, E3, 1.0f);
            float D01 = D0 * D1;
            float D23 = D2 * D3;
            float N01 = fmaf(c01.y, D1, c01.w * D0);
            float N23 = fmaf(c23.y, D3, c23.w * D2);
            float N   = fmaf(N01, D23, N23 * D01);
            float P   = D01 * D23;
            p = fmaf(N, asm_rcp(P), p);
        };

        int pp = gwave;
        if (pp >= npairs) return;
        IdxPair iA, iB;
        load_idx4(pp, iA, iB);
        bf16x8 fcA = gather(iA.c), frA = gather(iA.r);
        bf16x8 fcB = gather(iB.c), frB = gather(iB.r);
        int pn = pp + nwaves;
        IdxPair iAn, iBn;
        load_idx4(pn < npairs ? pn : npairs - 1, iAn, iBn);

        const f32x16 ZC = 0.0f;

        while (true) {
            // prefetch: gathers for pair+1, indices for pair+2
            bf16x8 fcAn = gather(iAn.c), frAn = gather(iAn.r);
            bf16x8 fcBn = gather(iBn.c), frBn = gather(iBn.r);
            int pnn = pn + nwaves;
            IdxPair iAnn, iBnn;
            load_idx4(pnn < npairs ? pnn : npairs - 1, iAnn, iBnn);

            // ---- tile A ----
            float pA = pbase;
            {
                f32x16 a0 = __builtin_amdgcn_mfma_f32_32x32x16_bf16(w1f00, fcA, ZC, 0, 0, 0);
                a0        = __builtin_amdgcn_mfma_f32_32x32x16_bf16(w1f01, frA, a0, 0, 0, 0);
                f32x16 a1 = __builtin_amdgcn_mfma_f32_32x32x16_bf16(w1f10, fcA, ZC, 0, 0, 0);
                a1        = __builtin_amdgcn_mfma_f32_32x32x16_bf16(w1f11, frA, a1, 0, 0, 0);
#pragma unroll
                for (int q = 0; q < 4; ++q) quad(a0, q * 4, cc[2 * q],     cc[2 * q + 1], pA);
#pragma unroll
                for (int q = 0; q < 4; ++q) quad(a1, q * 4, cc[8 + 2 * q], cc[9 + 2 * q], pA);
            }
            // ---- tile B ----
            float pB = pbase;
            {
                f32x16 a0 = __builtin_amdgcn_mfma_f32_32x32x16_bf16(w1f00, fcB, ZC, 0, 0, 0);
                a0        = __builtin_amdgcn_mfma_f32_32x32x16_bf16(w1f01, frB, a0, 0, 0, 0);
                f32x16 a1 = __builtin_amdgcn_mfma_f32_32x32x16_bf16(w1f10, fcB, ZC, 0, 0, 0);
                a1        = __builtin_amdgcn_mfma_f32_32x32x16_bf16(w1f11, frB, a1, 0, 0, 0);
#pragma unroll
                for (int q = 0; q < 4; ++q) quad(a0, q * 4, cc[2 * q],     cc[2 * q + 1], pB);
#pragma unroll
                for (int q = 0; q < 4; ++q) quad(a1, q * 4, cc[8 + 2 * q], cc[9 + 2 * q], pB);
            }

            // select-before-reduce: lane's own tile partial + cross partial from lane^32
            float own   = g ? pB : pA;
            float cross = g ? pA : pB;
            own += __shfl_xor(cross, 32);
            float z = own + bias2;
            float res = asm_rcp(1.0f + asm_exp2(-z * LOG2E));

            // e = pp*64 + lane: one unpredicated, fully-coalesced 256B store
            unsigned eoff = (((unsigned)pp << 6) + (unsigned)lane) << 2;
            *(float*)(outb + eoff) = res;

            if (pn >= npairs) break;
            pp = pn; pn = pnn;
            iAn = iAnn; iBn = iBnn;
            fcA = fcAn; frA = frAn; fcB = fcBn; frB = frBn;
        }
    };

    if (idx64) body(BC<true>{});
    else       body(BC<false>{});
}

// ===================== fallback single-tile kernel (E % 64 != 0) =====================
template <bool USE_XB, bool EXACT>
__global__ void __launch_bounds__(256)
edge_mlp1(const void* __restrict__ ei,
          const float* __restrict__ x,
          const unsigned short* __restrict__ xb,
          const float* __restrict__ W1,
          const float* __restrict__ b1,
          const float* __restrict__ W2,
          const float* __restrict__ b2,
          float* __restrict__ out,
          const int* __restrict__ flag,
          int E, int ntiles)
{
    __shared__ float2 tbl[64];

    const int lane = threadIdx.x & 63;
    const int l31  = lane & 31;
    const int g    = lane >> 5;
    const int gwave  = blockIdx.x * (blockDim.x >> 6) + (threadIdx.x >> 6);
    const int nwaves = gridDim.x * (blockDim.x >> 6);

    const int idx64 = flag ? flag[0] : 0;
    const float S = 2.0f * LOG2E;

    {
        int tid = threadIdx.x;
        if (tid < 64) {
            int tg = tid >> 5, tb = (tid >> 4) & 1, tj = tid & 15;
            int rowv = (tj & 3) + 8 * (tj >> 2) + 4 * tg;
            int h = 32 * tb + rowv;
            float2 cw;
            cw.x = exp2f(S * b1[h]);
            cw.y = -2.0f * W2[h];
            tbl[tid] = cw;
        }
    }

    bf16x8 w1f00, w1f01, w1f10, w1f11;
    {
        union { bf16x8 v; unsigned short u[8]; } t00, t01, t10, t11;
#pragma unroll
        for (int b = 0; b < 8; ++b) {
            int k0 = 8 * g + b;
            t00.u[b] = f2bf(S * W1[(k0)      * 64 + l31]);
            t01.u[b] = f2bf(S * W1[(16 + k0) * 64 + l31]);
            t10.u[b] = f2bf(S * W1[(k0)      * 64 + 32 + l31]);
            t11.u[b] = f2bf(S * W1[(16 + k0) * 64 + 32 + l31]);
        }
        w1f00 = t00.v; w1f01 = t01.v; w1f10 = t10.v; w1f11 = t11.v;
    }

    float pbase = 0.f;
#pragma unroll
    for (int j = 0; j < 16; ++j) {
        int rowv = (j & 3) + 8 * (j >> 2) + 4 * g;
        pbase += W2[rowv] + W2[32 + rowv];
    }
    const float bias2 = b2[0];

    __syncthreads();
    const float4* t4 = (const float4*)(&tbl[g * 32]);

    const char* xbb  = (const char*)xb;
    const char* outb = (char*)out;
    const unsigned g16 = (unsigned)g << 4;

    auto body = [&](auto bc) {
        constexpr bool IDX64 = decltype(bc)::value;
        const unsigned sh = IDX64 ? 3u : 2u;
        const char* eiR = (const char*)ei;
        const char* eiC = (const char*)ei + ((size_t)E << sh);

        auto load_idx = [&](int tt) -> IdxPair {
            int e = tt * 32 + l31;
            unsigned ec;
            if (EXACT) ec = (unsigned)e;
            else       ec = (unsigned)(e < E ? e : E - 1);
            unsigned off = ec << sh;
            IdxPair ip;
            ip.r = *(const int*)(eiR + off);
            ip.c = *(const int*)(eiC + off);
            return ip;
        };
        auto gather = [&](int node) -> bf16x8 {
            if (USE_XB) {
                unsigned off = ((unsigned)node << 5) + g16;
                return *(const bf16x8*)(xbb + off);
            } else {
                const float* px = x + (size_t)node * 16 + 8 * g;
                f32x4 v0 = *(const f32x4*)px;
                f32x4 v1 = *(const f32x4*)(px + 4);
                union { bf16x8 v; unsigned short u[8]; } t;
#pragma unroll
                for (int b = 0; b < 4; ++b) { t.u[b] = f2bf(v0[b]); t.u[b + 4] = f2bf(v1[b]); }
                return t.v;
            }
        };

        auto quad = [&](const f32x16& A, int k, float4 c01, float4 c23, float& p) {
            float E0 = asm_exp2(A[k]);
            float E1 = asm_exp2(A[k + 1]);
            float E2 = asm_exp2(A[k + 2]);
            float E3 = asm_exp2(A[k + 3]);
            float D0 = fmaf(c01.x, E0, 1.0f);
            float D1 = fmaf(c01.z, E1, 1.0f);
            float D2 = fmaf(c23.x, E2, 1.0f);
            float D3 = fmaf(c23.z, E3, 1.0f);
            float D01 = D0 * D1;
            float D23 = D2 * D3;
            float N01 = fmaf(c01.y, D1, c01.w * D0);
            float N23 = fmaf(c23.y, D3, c23.w * D2);
            float N   = fmaf(N01, D23, N23 * D01);
            float P   = D01 * D23;
            p = fmaf(N, asm_rcp(P), p);
        };

        int t = gwave;
        if (t >= ntiles) return;
        IdxPair ic = load_idx(t);
        bf16x8 fc = gather(ic.c);
        bf16x8 fr = gather(ic.r);
        int tn = t + nwaves;
        IdxPair inx = load_idx(tn < ntiles ? tn : ntiles - 1);

        const f32x16 ZC = 0.0f;

        while (true) {
            bf16x8 fcn = gather(inx.c);
            bf16x8 frn = gather(inx.r);
            int tnn = tn + nwaves;
            IdxPair inn = load_idx(tnn < ntiles ? tnn : ntiles - 1);

            f32x16 acc0 = __builtin_amdgcn_mfma_f32_32x32x16_bf16(w1f00, fc, ZC, 0, 0, 0);
            acc0        = __builtin_amdgcn_mfma_f32_32x32x16_bf16(w1f01, fr, acc0, 0, 0, 0);
            f32x16 acc1 = __builtin_amdgcn_mfma_f32_32x32x16_bf16(w1f10, fc, ZC, 0, 0, 0);
            acc1        = __builtin_amdgcn_mfma_f32_32x32x16_bf16(w1f11, fr, acc1, 0, 0, 0);

            float p = pbase;
#pragma unroll
            for (int q = 0; q < 4; ++q) quad(acc0, q * 4, t4[2 * q],     t4[2 * q + 1], p);
#pragma unroll
            for (int q = 0; q < 4; ++q) quad(acc1, q * 4, t4[8 + 2 * q], t4[9 + 2 * q], p);

            p += __shfl_xor(p, 32);
            float z = p + bias2;
            float res = asm_rcp(1.0f + asm_exp2(-z * LOG2E));

            unsigned eoff = ((unsigned)(t * 32 + l31)) << 2;
            if (EXACT) {
                if (lane < 32) *(float*)(outb + eoff) = res;
            } else {
                if (lane < 32 && (t * 32 + l31) < E) *(float*)(outb + eoff) = res;
            }

            if (tn >= ntiles) break;
            t = tn; tn = tnn;
            inx = inn; fc = fcn; fr = frn;
        }
    };

    if (idx64) body(BC<true>{});
    else       body(BC<false>{});
}

extern "C" void kernel_launch(void* const* d_in, const int* in_sizes, int n_in,
                              void* d_out, int out_size, void* d_ws, size_t ws_size,
                              hipStream_t stream)
{
    const float* x  = (const float*)d_in[0];
    const void*  ei = d_in[1];
    const float* W1 = (const float*)d_in[2];
    const float* b1 = (const float*)d_in[3];
    const float* W2 = (const float*)d_in[4];
    const float* b2 = (const float*)d_in[5];
    float* out = (float*)d_out;

    const int E      = in_sizes[1] / 2;
    const int nx     = in_sizes[0];
    const int ntiles = (E + 31) / 32;

    int* flag = nullptr;
    unsigned short* xb = nullptr;
    bool use_xb = false;
    if (ws_size >= 4) flag = (int*)d_ws;
    if (ws_size >= 256 + (size_t)nx * 2) {
        xb = (unsigned short*)((char*)d_ws + 256);
        use_xb = true;
    }

    if (use_xb) {
        int nth = (nx + 3) / 4;
        prep<<<(nth + 255) / 256, 256, 0, stream>>>(x, xb, nx, (const unsigned*)ei, flag);
    } else if (flag) {
        detect_idx64<<<1, 64, 0, stream>>>((const unsigned*)ei, flag);
    }

    if ((E & 63) == 0) {
        const int npairs = E / 64;
        int blocks = 768;                      // best measured grid (R8: 60.3us)
        if (npairs < blocks * 4) blocks = (npairs + 3) / 4;
        if (blocks < 1) blocks = 1;
        if (use_xb)
            edge_mlp_pair<true ><<<blocks, 256, 0, stream>>>(ei, x, xb, W1, b1, W2, b2, out, flag, E, npairs);
        else
            edge_mlp_pair<false><<<blocks, 256, 0, stream>>>(ei, x, xb, W1, b1, W2, b2, out, flag, E, npairs);
    } else {
        const bool exact = (E % 32) == 0;
        int blocks = 1250;
        if (ntiles < blocks * 4) blocks = (ntiles + 3) / 4;
        if (blocks < 1) blocks = 1;
        if (use_xb) {
            if (exact) edge_mlp1<true , true ><<<blocks, 256, 0, stream>>>(ei, x, xb, W1, b1, W2, b2, out, flag, E, ntiles);
            else       edge_mlp1<true , false><<<blocks, 256, 0, stream>>>(ei, x, xb, W1, b1, W2, b2, out, flag, E, ntiles);
        } else {
            if (exact) edge_mlp1<false, true ><<<blocks, 256, 0, stream>>>(ei, x, xb, W1, b1, W2, b2, out, flag, E, ntiles);
            else       edge_mlp1<false, false><<<blocks, 256, 0, stream>>>(ei, x, xb, W1, b1, W2, b2, out, flag, E, ntiles);
        }
    }
}